// Round 17
// baseline (189.577 us; speedup 1.0000x reference)
//
#include <hip/hip_runtime.h>
#include <math.h>

typedef unsigned short ushort_t;
typedef __attribute__((ext_vector_type(8))) short short8;
typedef __attribute__((ext_vector_type(4))) float f32x4;

#define B_  16
#define HW_ 1024
#define C_  64
#define NC_ 5
#define D1_ 96
#define NH_ 4
#define DH_ 64

#define MFMA32(A,B,C) __builtin_amdgcn_mfma_f32_16x16x32_bf16(A,B,C,0,0,0)

__device__ __forceinline__ ushort_t f2bf(float f) {
    unsigned u = __float_as_uint(f);
    u = u + 0x7fffu + ((u >> 16) & 1u);   // round-to-nearest-even
    return (ushort_t)(u >> 16);
}

__device__ __forceinline__ unsigned pack2_trunc(float lo, float hi) {
    return (__float_as_uint(hi) & 0xffff0000u) | (__float_as_uint(lo) >> 16);
}
__device__ __forceinline__ unsigned pack2_rne(float lo, float hi) {
    return ((unsigned)f2bf(hi) << 16) | (unsigned)f2bf(lo);
}
__device__ __forceinline__ float bf_lo(unsigned u) { return __uint_as_float(u << 16); }
__device__ __forceinline__ float bf_hi(unsigned u) { return __uint_as_float(u & 0xffff0000u); }

// async global->LDS, 16B per lane; LDS dest = wave-uniform base + lane*16
__device__ __forceinline__ void gload16(const ushort_t* g, ushort_t* l) {
    __builtin_amdgcn_global_load_lds(
        (const __attribute__((address_space(1))) unsigned int*)g,
        (__attribute__((address_space(3))) unsigned int*)l,
        16, 0, 0);
}

// ---------------- K1: logits + class-softmax (4-wave split) + folded k0(F) + kh/vh precompute ------
// blocks 0..255: main k1. blocks 256..263: fcT frag chunks. block 264: kh/vh = mem@wk/wv (batch-
// independent — hoisted out of k3 where every block redid the 96-FMA serial chains).
__global__ __launch_bounds__(256) void k1_logits(const float* __restrict__ x,
                                                 const float* __restrict__ wb_w,
                                                 const float* __restrict__ wb_b,
                                                 const float* __restrict__ fc2,
                                                 const float* __restrict__ mem,
                                                 const float* __restrict__ wk, const float* __restrict__ bk,
                                                 const float* __restrict__ wv, const float* __restrict__ bv,
                                                 float* __restrict__ logitsT,
                                                 float* __restrict__ w1,
                                                 ushort_t* __restrict__ F,
                                                 float* __restrict__ khG, float* __restrict__ vhG) {
    int t = threadIdx.x;
    if (blockIdx.x >= 256) {
        int xb2 = blockIdx.x - 256;
        if (xb2 < 8) {               // fcT fragment chunks
            int c = xb2 * 256 + t;
            int l = c & 63, s = (c >> 6) & 7, n = c >> 9;
            int col = n * 16 + (l & 15);
            int k0 = s * 32 + (l >> 4) * 8;
            union { ushort_t us[8]; uint4 u; } pk;
#pragma unroll
            for (int j = 0; j < 8; j++) pk.us[j] = f2bf(fc2[(k0 + j) * 64 + col]);
            *(uint4*)(F + (size_t)c * 8) = pk.u;
        } else {                     // kh/vh precompute
            for (int idx = t; idx < NC_ * D1_; idx += 256) {
                int i = idx / D1_, k = idx % D1_;
                float a = bk[k];
                for (int d = 0; d < D1_; d++) a += mem[i * D1_ + d] * wk[d * D1_ + k];
                khG[idx] = a;
            }
            for (int idx = t; idx < NC_ * DH_; idx += 256) {
                int i = idx / DH_, dv = idx % DH_;
                float a = bv[dv];
                for (int d = 0; d < D1_; d++) a += mem[i * D1_ + d] * wv[d * DH_ + dv];
                vhG[idx] = a;
            }
        }
        return;
    }
    __shared__ float part[4][64][6];     // pad 6 -> 2-way worst (free)
    int w = t >> 6, lane = t & 63;
    int b = blockIdx.x >> 4;
    int hw = (blockIdx.x & 15) * 64 + lane;
    const float* xb = x + ((size_t)b * C_ + w * 16) * HW_;
    float acc[NC_] = {0.f, 0.f, 0.f, 0.f, 0.f};
#pragma unroll
    for (int c = 0; c < 16; c++) {
        float xv = xb[c * HW_ + hw];
        const float* wp = wb_w + (w * 16 + c) * NC_;   // wave-uniform -> scalar loads
#pragma unroll
        for (int j = 0; j < NC_; j++) acc[j] += xv * wp[j];
    }
#pragma unroll
    for (int j = 0; j < NC_; j++) part[w][lane][j] = acc[j];
    __syncthreads();
    if (w == 0) {
        float a[NC_];
#pragma unroll
        for (int j = 0; j < NC_; j++)
            a[j] = wb_b[j] + acc[j] + part[1][lane][j] + part[2][lane][j] + part[3][lane][j];
        float m = a[0];
#pragma unroll
        for (int j = 1; j < NC_; j++) m = fmaxf(m, a[j]);
        float e[NC_], s = 0.f;
#pragma unroll
        for (int j = 0; j < NC_; j++) { e[j] = __expf(a[j] - m); s += e[j]; }
        float inv = 1.f / s;
        int idx = b * HW_ + hw;
#pragma unroll
        for (int j = 0; j < NC_; j++) {
            logitsT[((size_t)b * NC_ + j) * HW_ + hw] = a[j];
            w1[(size_t)idx * NC_ + j] = e[j] * inv;
        }
    }
}

// ---------------- K2: fused softmax-over-HW + pooling: cf1[b,c,ch] ----------------
__global__ __launch_bounds__(256) void k2b_pool(const float* __restrict__ x,
                                                const float* __restrict__ logitsT,
                                                float* __restrict__ cf1) {
    __shared__ float pl[NC_ * HW_];     // 20 KB
    __shared__ float sinv[NC_];
    int t = threadIdx.x;
    int b = blockIdx.x >> 4, chg = blockIdx.x & 15;
    const float* lp = logitsT + (size_t)b * NC_ * HW_;
    for (int i = t * 4; i < NC_ * HW_; i += 1024)
        *(float4*)(pl + i) = *(const float4*)(lp + i);
    __syncthreads();
    int w = t >> 6, lane = t & 63;
    for (int r = w; r < NC_; r += 4) {
        float m = -1e30f;
        for (int i = lane; i < HW_; i += 64) m = fmaxf(m, pl[r * HW_ + i]);
#pragma unroll
        for (int off = 1; off < 64; off <<= 1) m = fmaxf(m, __shfl_xor(m, off, 64));
        float s = 0.f;
        for (int i = lane; i < HW_; i += 64) {
            float e = __expf(pl[r * HW_ + i] - m);
            pl[r * HW_ + i] = e;
            s += e;
        }
#pragma unroll
        for (int off = 1; off < 64; off <<= 1) s += __shfl_xor(s, off, 64);
        if (lane == 0) sinv[r] = 1.f / s;
    }
    __syncthreads();
    int ch = chg * 4 + w;
    const float* xc = x + ((size_t)b * C_ + ch) * HW_;
    float acc[NC_] = {0.f, 0.f, 0.f, 0.f, 0.f};
#pragma unroll
    for (int i = 0; i < HW_ / 64; i++) {
        int hw = i * 64 + lane;
        float xv = xc[hw];
#pragma unroll
        for (int c = 0; c < NC_; c++) acc[c] += xv * pl[c * HW_ + hw];
    }
#pragma unroll
    for (int c = 0; c < NC_; c++) {
        float a = acc[c];
#pragma unroll
        for (int off = 1; off < 64; off <<= 1) a += __shfl_xor(a, off, 64);
        if (lane == 0) cf1[((size_t)b * NC_ + c) * C_ + ch] = a * sinv[c];
    }
}

// ---------------- K3: MHA1 + residual + LN, per batch (kh/vh now loaded, not computed) ----------
__global__ __launch_bounds__(256) void k3_mha1(const float* __restrict__ cf1,
                                               const float* __restrict__ wq, const float* __restrict__ bq,
                                               const float* __restrict__ khG, const float* __restrict__ vhG,
                                               const float* __restrict__ fc, const float* __restrict__ fcb,
                                               const float* __restrict__ lng, const float* __restrict__ lnb,
                                               float* __restrict__ cfs) {
    __shared__ float cs[NC_ * C_];
    __shared__ float kh[NC_ * D1_];
    __shared__ float vh[NC_ * DH_];
    __shared__ float q[NC_ * D1_];
    __shared__ float sc[NC_ * NC_];
    __shared__ float pp[NC_ * NC_];
    __shared__ float o[NC_ * C_];
    __shared__ float z[NC_ * C_];
    __shared__ float mu[NC_], rs[NC_];
    int t = threadIdx.x, b = blockIdx.x;
    for (int i = t; i < NC_ * C_; i += 256) cs[i] = cf1[(size_t)b * NC_ * C_ + i];
    for (int idx = t; idx < NC_ * D1_; idx += 256) kh[idx] = khG[idx];
    for (int idx = t; idx < NC_ * DH_; idx += 256) vh[idx] = vhG[idx];
    __syncthreads();
    for (int idx = t; idx < NC_ * D1_; idx += 256) {
        int i = idx / D1_, k = idx % D1_;
        float a = bq[k];
        for (int c = 0; c < C_; c++) a += cs[i * C_ + c] * wq[c * D1_ + k];
        q[idx] = a;
    }
    __syncthreads();
    if (t < NC_ * NC_) {
        int i = t / NC_, j = t % NC_;
        float a = 0.f;
        for (int k = 0; k < D1_; k++) a += q[i * D1_ + k] * kh[j * D1_ + k];
        sc[t] = a * 0.1020620726159657f;     // 1/sqrt(96)
    }
    __syncthreads();
    if (t < NC_) {
        float m = sc[t * NC_];
        for (int j = 1; j < NC_; j++) m = fmaxf(m, sc[t * NC_ + j]);
        float e[NC_], s = 0.f;
        for (int j = 0; j < NC_; j++) { e[j] = __expf(sc[t * NC_ + j] - m); s += e[j]; }
        float inv = 1.f / s;
        for (int j = 0; j < NC_; j++) pp[t * NC_ + j] = e[j] * inv;
    }
    __syncthreads();
    for (int idx = t; idx < NC_ * C_; idx += 256) {
        int i = idx / C_, dv = idx % C_;
        float a = 0.f;
        for (int j = 0; j < NC_; j++) a += pp[i * NC_ + j] * vh[j * C_ + dv];
        o[idx] = a;
    }
    __syncthreads();
    for (int idx = t; idx < NC_ * C_; idx += 256) {
        int i = idx / C_, dd = idx % C_;
        float a = fcb[dd] + cs[idx];
        for (int c2 = 0; c2 < C_; c2++) a += o[i * C_ + c2] * fc[c2 * C_ + dd];
        z[idx] = a;
    }
    __syncthreads();
    if (t < NC_) {
        float s = 0.f;
        for (int d = 0; d < C_; d++) s += z[t * C_ + d];
        float mm = s / C_;
        float v = 0.f;
        for (int d = 0; d < C_; d++) { float dd2 = z[t * C_ + d] - mm; v += dd2 * dd2; }
        mu[t] = mm; rs[t] = rsqrtf(v / C_ + 1e-6f);
    }
    __syncthreads();
    for (int idx = t; idx < NC_ * C_; idx += 256) {
        int i = idx / C_, dd = idx % C_;
        cfs[(size_t)b * NC_ * C_ + idx] = (z[idx] - mu[i]) * rs[i] * lng[dd] + lnb[dd];
    }
}

// ---------------- K5: MFMA projection GEMM (inline redistribution + Q/K/V) — R13 version ----------
__global__ __launch_bounds__(256) void k5_mfma(const float* __restrict__ w1,
                                               const float* __restrict__ cfs,
                                               const float* __restrict__ wq, const float* __restrict__ bq,
                                               const float* __restrict__ wk, const float* __restrict__ bk,
                                               const float* __restrict__ wv, const float* __restrict__ bv,
                                               ushort_t* __restrict__ Qb, ushort_t* __restrict__ Kb,
                                               ushort_t* __restrict__ Vt) {
    __shared__ ushort_t Af[64][68];      // cf rows, bf16
    __shared__ ushort_t Wt[256][68];     // W^T [n][k], bf16
    int t = threadIdx.x;
    int which = blockIdx.y;
    int m0 = blockIdx.x * 64;
    int b = m0 >> 10, lbase = m0 & 1023;
    {
        int r = t >> 2, ks = (t & 3) * 16;
        const float* cp = cfs + (size_t)b * NC_ * C_;
        const float* w1p = w1 + (size_t)(m0 + r) * NC_;
        float v0 = w1p[0], v1 = w1p[1], v2 = w1p[2], v3 = w1p[3], v4 = w1p[4];
#pragma unroll
        for (int j = 0; j < 16; j += 2) {
            int k = ks + j;
            float e0 = v0 * cp[k]       + v1 * cp[64 + k]     + v2 * cp[128 + k]
                     + v3 * cp[192 + k] + v4 * cp[256 + k];
            float e1 = v0 * cp[k + 1]     + v1 * cp[64 + k + 1] + v2 * cp[128 + k + 1]
                     + v3 * cp[192 + k + 1] + v4 * cp[256 + k + 1];
            *(unsigned*)&Af[r][k] = pack2_rne(e0, e1);
        }
    }
    const float* W = (which == 0) ? wq : (which == 1) ? wk : wv;
    {
        int n = t;
#pragma unroll
        for (int k = 0; k < 64; k += 2) {
            *(unsigned*)&Wt[n][k] = pack2_rne(W[k * 256 + n], W[(k + 1) * 256 + n]);
        }
    }
    __syncthreads();
    int lane = t & 63, w = t >> 6;
    int l15 = lane & 15, quad = lane >> 4;
    if (which < 2) {
        const float* bias = (which == 0) ? bq : bk;
        float scale = (which == 0) ? 0.18033688011112042f : 1.0f;  // log2e/8 folded into Q
        ushort_t* dst = (which == 0) ? Qb : Kb;
        short8 a0[4], a1[4];
#pragma unroll
        for (int mi = 0; mi < 4; mi++) {
            a0[mi] = *(const short8*)&Af[mi * 16 + l15][quad * 8];
            a1[mi] = *(const short8*)&Af[mi * 16 + l15][32 + quad * 8];
        }
#pragma unroll
        for (int nt = 0; nt < 4; nt++) {
            int ni = w * 4 + nt;
            short8 b0 = *(const short8*)&Wt[ni * 16 + l15][quad * 8];
            short8 b1 = *(const short8*)&Wt[ni * 16 + l15][32 + quad * 8];
            int n = ni * 16 + l15;
            float bb = bias[n];
            int h = n >> 6, dd = n & 63;
#pragma unroll
            for (int mi = 0; mi < 4; mi++) {
                f32x4 z = {0, 0, 0, 0};
                f32x4 dv4 = MFMA32(a0[mi], b0, z);
                dv4 = MFMA32(a1[mi], b1, dv4);
                size_t base = ((size_t)(b * NH_ + h) * HW_ + (lbase + mi * 16 + quad * 4)) * DH_ + dd;
#pragma unroll
                for (int r = 0; r < 4; r++)
                    dst[base + (size_t)r * DH_] = f2bf((dv4[r] + bb) * scale);
            }
        }
    } else {
        short8 a0[4], a1[4];
#pragma unroll
        for (int mt = 0; mt < 4; mt++) {
            int mi = w * 4 + mt;
            a0[mt] = *(const short8*)&Wt[mi * 16 + l15][quad * 8];
            a1[mt] = *(const short8*)&Wt[mi * 16 + l15][32 + quad * 8];
        }
#pragma unroll
        for (int nt = 0; nt < 4; nt++) {
            short8 b0 = *(const short8*)&Af[nt * 16 + l15][quad * 8];
            short8 b1 = *(const short8*)&Af[nt * 16 + l15][32 + quad * 8];
#pragma unroll
            for (int mt = 0; mt < 4; mt++) {
                int mi = w * 4 + mt;
                f32x4 z = {0, 0, 0, 0};
                f32x4 dv4 = MFMA32(a0[mt], b0, z);
                dv4 = MFMA32(a1[mt], b1, dv4);
                int h = mi >> 2;
#pragma unroll
                for (int r = 0; r < 4; r++) {
                    int nw = mi * 16 + quad * 4 + r;
                    int dv = nw & 63;
                    Vt[((size_t)(b * NH_ + h) * DH_ + dv) * HW_ + lbase + nt * 16 + l15] =
                        f2bf(dv4[r] + bv[nw]);
                }
            }
        }
    }
}

// ---------------- K6: flash attention — async LDS staging, split-K4, 4 q-tiles/wave ----------
// split-K 4 (grid 1024, 4 blocks/CU): doubles TLP for barrier overlap, halves each wave's
// serial K-chain (8 iters). Partials combine linearly in k7 (no-max softmax).
__global__ __launch_bounds__(256) void k6_attn(const ushort_t* __restrict__ Qb,
                                               const ushort_t* __restrict__ Kb,
                                               const ushort_t* __restrict__ Vt,
                                               ushort_t* __restrict__ aoPb,
                                               float* __restrict__ sPb) {
    __shared__ ushort_t Kst[2][8][512];     // 16 KB
    int t = threadIdx.x;
    int w = t >> 6;
    int lane = t & 63;
    int l15 = lane & 15;
    int quad = lane >> 4;
    // decode (grid 1024): [2:0]=bh_lo, [5:3]=bh_hi, [7:6]=kq, [9:8]=qt ; L%8==bh%8 swizzle
    int L = blockIdx.x;
    int bh = ((L >> 3) & 7) * 8 + (L & 7);
    int r2 = L >> 6;
    int kq = r2 & 3;
    int qt = r2 >> 2;                    // 0..3
    int b = bh >> 2, h = bh & 3;
    const ushort_t* Qp = Qb + (size_t)bh * HW_ * DH_;
    const ushort_t* Kp = Kb + (size_t)bh * HW_ * DH_;
    const ushort_t* Vp = Vt + (size_t)bh * DH_ * HW_;
    int row0 = qt * 256 + w * 16;
    short8 q0[4], q1[4];
#pragma unroll
    for (int tl = 0; tl < 4; tl++) {
        const ushort_t* qp = Qp + (size_t)(row0 + tl * 64 + l15) * DH_ + quad * 8;
        q0[tl] = *(const short8*)(qp);
        q1[tl] = *(const short8*)(qp + 32);
    }
    int f0 = ((l15 >> 2) * 8) + (l15 & 3);
    int kstart = kq * 256;
    const ushort_t* K0p = Kp + (size_t)(kstart + f0) * DH_ + quad * 8;
    const ushort_t* K1p = Kp + (size_t)(kstart + f0 + 4) * DH_ + quad * 8;
    const ushort_t* Vp0 = Vp + (size_t)(0 * 16 + l15) * HW_ + kstart + quad * 8;
    const ushort_t* Vp1 = Vp + (size_t)(1 * 16 + l15) * HW_ + kstart + quad * 8;
    const ushort_t* Vp2 = Vp + (size_t)(2 * 16 + l15) * HW_ + kstart + quad * 8;
    const ushort_t* Vp3 = Vp + (size_t)(3 * 16 + l15) * HW_ + kstart + quad * 8;
    auto stage = [&](int kt, int bb) {
        size_t koff = (size_t)kt * 32 * DH_;
        int kb32 = kt * 32;
        if (w == 0) {
            gload16(K0p + koff,      &Kst[bb][0][0]);
            gload16(K0p + koff + 32, &Kst[bb][1][0]);
        } else if (w == 1) {
            gload16(K1p + koff,      &Kst[bb][2][0]);
            gload16(K1p + koff + 32, &Kst[bb][3][0]);
        } else if (w == 2) {
            gload16(Vp0 + kb32, &Kst[bb][4][0]);
            gload16(Vp1 + kb32, &Kst[bb][5][0]);
        } else {
            gload16(Vp2 + kb32, &Kst[bb][6][0]);
            gload16(Vp3 + kb32, &Kst[bb][7][0]);
        }
    };
    const short ONE = (short)0x3F80;      // bf16 1.0
    short8 ones = {ONE, ONE, ONE, ONE, ONE, ONE, ONE, ONE};
    f32x4 o0[4], o1[4], o2[4], o3[4], oS[4];
#pragma unroll
    for (int tl = 0; tl < 4; tl++) {
        o0[tl] = (f32x4){0,0,0,0}; o1[tl] = (f32x4){0,0,0,0};
        o2[tl] = (f32x4){0,0,0,0}; o3[tl] = (f32x4){0,0,0,0};
        oS[tl] = (f32x4){0,0,0,0};
    }
    stage(0, 0);
    for (int kt = 0; kt < 8; kt++) {
        int bb = kt & 1;
        __syncthreads();                     // stage(kt) complete
        if (kt < 7) stage(kt + 1, bb ^ 1);   // flies during compute below
        const ushort_t* S = &Kst[bb][0][0];
        short8 ka0 = *(const short8*)(S + 0 * 512 + lane * 8);
        short8 ka1 = *(const short8*)(S + 1 * 512 + lane * 8);
        short8 kb0 = *(const short8*)(S + 2 * 512 + lane * 8);
        short8 kb1 = *(const short8*)(S + 3 * 512 + lane * 8);
        short8 v0  = *(const short8*)(S + 4 * 512 + lane * 8);
        short8 v1  = *(const short8*)(S + 5 * 512 + lane * 8);
        short8 v2  = *(const short8*)(S + 6 * 512 + lane * 8);
        short8 v3  = *(const short8*)(S + 7 * 512 + lane * 8);
        f32x4 z = {0,0,0,0};
#pragma unroll
        for (int tl = 0; tl < 4; tl++) {
            f32x4 s0 = MFMA32(ka0, q0[tl], z);  s0 = MFMA32(ka1, q1[tl], s0);
            f32x4 s1 = MFMA32(kb0, q0[tl], z);  s1 = MFMA32(kb1, q1[tl], s1);
            float p0 = exp2f(s0[0]), p1 = exp2f(s0[1]), p2 = exp2f(s0[2]), p3 = exp2f(s0[3]);
            float p4 = exp2f(s1[0]), p5 = exp2f(s1[1]), p6 = exp2f(s1[2]), p7 = exp2f(s1[3]);
            union { short8 v; unsigned u[4]; } pf;
            pf.u[0] = pack2_trunc(p0, p1);  pf.u[1] = pack2_trunc(p2, p3);
            pf.u[2] = pack2_trunc(p4, p5);  pf.u[3] = pack2_trunc(p6, p7);
            o0[tl] = MFMA32(v0, pf.v, o0[tl]);
            o1[tl] = MFMA32(v1, pf.v, o1[tl]);
            o2[tl] = MFMA32(v2, pf.v, o2[tl]);
            o3[tl] = MFMA32(v3, pf.v, o3[tl]);
            oS[tl] = MFMA32(ones, pf.v, oS[tl]);
        }
    }
    ushort_t* aoP = aoPb + (size_t)kq * 4194304;
    float* sP = sPb + (size_t)kq * 65536;
#pragma unroll
    for (int tl = 0; tl < 4; tl++) {
        int rowg = row0 + tl * 64 + l15;
        ushort_t* aop = aoP + ((size_t)(b * HW_ + rowg)) * 256 + h * 64 + quad * 4;
        uint2 u;
        u.x = pack2_trunc(o0[tl][0], o0[tl][1]); u.y = pack2_trunc(o0[tl][2], o0[tl][3]);
        *(uint2*)(aop + 0) = u;
        u.x = pack2_trunc(o1[tl][0], o1[tl][1]); u.y = pack2_trunc(o1[tl][2], o1[tl][3]);
        *(uint2*)(aop + 16) = u;
        u.x = pack2_trunc(o2[tl][0], o2[tl][1]); u.y = pack2_trunc(o2[tl][2], o2[tl][3]);
        *(uint2*)(aop + 32) = u;
        u.x = pack2_trunc(o3[tl][0], o3[tl][1]); u.y = pack2_trunc(o3[tl][2], o3[tl][3]);
        *(uint2*)(aop + 48) = u;
        if (quad == 0)
            sP[(size_t)(b * HW_ + rowg) * NH_ + h] = oS[tl][0];
    }
}

// ---------------- K7: combine 4 partials -> MFMA GEMM vs fc + residual + LN -> out ----------------
__global__ __launch_bounds__(256) void k7_final(const ushort_t* __restrict__ aoPb,
                                                const float* __restrict__ sPb,
                                                const float* __restrict__ w1,
                                                const float* __restrict__ cfs,
                                                const ushort_t* __restrict__ F,
                                                const float* __restrict__ fcb,
                                                const float* __restrict__ lng, const float* __restrict__ lnb,
                                                float* __restrict__ out) {
    __shared__ ushort_t Afr[512 * 8];     // 8 KB fragment-order A
    __shared__ float rinv[64];
    __shared__ float T[16][68];           // MFMA result f32 (padded)
    __shared__ float To[64 * 17];         // output transpose buffer
    int t = threadIdx.x, w = t >> 6, lane = t & 63;
    int m0 = blockIdx.x * 16, b = m0 >> 10;   // m0 is the GLOBAL row index
    if (t < 64) {
        int row = t >> 2, hh = t & 3;
        size_t si = (size_t)(m0 + row) * NH_ + hh;
        float s = sPb[si] + sPb[65536 + si] + sPb[2 * 65536 + si] + sPb[3 * 65536 + si];
        rinv[t] = 1.f / s;
    }
    __syncthreads();
#pragma unroll
    for (int cc = t; cc < 512; cc += 256) {
        int s = cc >> 6, l = cc & 63;
        int row = l & 15, col0 = s * 32 + (l >> 4) * 8;
        int hh = col0 >> 6;
        size_t base = (size_t)(m0 + row) * 256 + col0;
        uint4 a0 = *(const uint4*)(aoPb + base);
        uint4 a1 = *(const uint4*)(aoPb + 4194304 + base);
        uint4 a2 = *(const uint4*)(aoPb + 2 * 4194304 + base);
        uint4 a3 = *(const uint4*)(aoPb + 3 * 4194304 + base);
        float r = rinv[row * 4 + hh];
        uint4 pk;
        pk.x = pack2_trunc((bf_lo(a0.x) + bf_lo(a1.x) + bf_lo(a2.x) + bf_lo(a3.x)) * r,
                           (bf_hi(a0.x) + bf_hi(a1.x) + bf_hi(a2.x) + bf_hi(a3.x)) * r);
        pk.y = pack2_trunc((bf_lo(a0.y) + bf_lo(a1.y) + bf_lo(a2.y) + bf_lo(a3.y)) * r,
                           (bf_hi(a0.y) + bf_hi(a1.y) + bf_hi(a2.y) + bf_hi(a3.y)) * r);
        pk.z = pack2_trunc((bf_lo(a0.z) + bf_lo(a1.z) + bf_lo(a2.z) + bf_lo(a3.z)) * r,
                           (bf_hi(a0.z) + bf_hi(a1.z) + bf_hi(a2.z) + bf_hi(a3.z)) * r);
        pk.w = pack2_trunc((bf_lo(a0.w) + bf_lo(a1.w) + bf_lo(a2.w) + bf_lo(a3.w)) * r,
                           (bf_hi(a0.w) + bf_hi(a1.w) + bf_hi(a2.w) + bf_hi(a3.w)) * r);
        *(uint4*)&Afr[(size_t)cc * 8] = pk;
    }
    __syncthreads();
    f32x4 acc = {0, 0, 0, 0};
#pragma unroll
    for (int s = 0; s < 8; s++) {
        short8 a = *(const short8*)&Afr[(s * 64 + lane) * 8];
        short8 bf8 = *(const short8*)(F + ((size_t)(w * 8 + s) * 64 + lane) * 8);
        acc = MFMA32(a, bf8, acc);
    }
    {
        int l15 = lane & 15, quad = lane >> 4;
#pragma unroll
        for (int r = 0; r < 4; r++) T[quad * 4 + r][w * 16 + l15] = acc[r];
    }
    __syncthreads();
    int d = lane;
    float g = lng[d], be = lnb[d], bias = fcb[d];
    const float* cp = cfs + (size_t)b * NC_ * C_;
#pragma unroll
    for (int j = 0; j < 4; j++) {
        int row = w * 4 + j;
        const float* w1p = w1 + (size_t)(m0 + row) * NC_;
        float a = bias + T[row][d];
#pragma unroll
        for (int c = 0; c < NC_; c++) a += w1p[c] * cp[c * 64 + d];
        float s1 = a, s2 = a * a;
#pragma unroll
        for (int off = 1; off < 64; off <<= 1) {
            s1 += __shfl_xor(s1, off, 64);
            s2 += __shfl_xor(s2, off, 64);
        }
        float mu = s1 * (1.f / 64.f);
        float var = s2 * (1.f / 64.f) - mu * mu;
        float rstd = rsqrtf(var + 1e-6f);
        To[d * 17 + row] = (a - mu) * rstd * g + be;
    }
    __syncthreads();
    int ch = t >> 2, part = t & 3;
    int hw0 = m0 & 1023;
    float4 v = {To[ch * 17 + part * 4 + 0], To[ch * 17 + part * 4 + 1],
                To[ch * 17 + part * 4 + 2], To[ch * 17 + part * 4 + 3]};
    *(float4*)&out[((size_t)b * 64 + ch) * 1024 + hw0 + part * 4] = v;
}

// ---------------- launcher: 6 dispatches ----------------
extern "C" void kernel_launch(void* const* d_in, const int* in_sizes, int n_in,
                              void* d_out, int out_size, void* d_ws, size_t ws_size,
                              hipStream_t stream) {
    const float* x      = (const float*)d_in[0];
    const float* memory = (const float*)d_in[1];
    const float* wb_w   = (const float*)d_in[2];
    const float* wb_b   = (const float*)d_in[3];
    const float* a1_wq  = (const float*)d_in[4];
    const float* a1_bq  = (const float*)d_in[5];
    const float* a1_wk  = (const float*)d_in[6];
    const float* a1_bk  = (const float*)d_in[7];
    const float* a1_wv  = (const float*)d_in[8];
    const float* a1_bv  = (const float*)d_in[9];
    const float* a1_fc  = (const float*)d_in[10];
    const float* a1_fcb = (const float*)d_in[11];
    const float* a1_ln_g = (const float*)d_in[12];
    const float* a1_ln_b = (const float*)d_in[13];
    const float* a2_wq  = (const float*)d_in[14];
    const float* a2_bq  = (const float*)d_in[15];
    const float* a2_wk  = (const float*)d_in[16];
    const float* a2_bk  = (const float*)d_in[17];
    const float* a2_wv  = (const float*)d_in[18];
    const float* a2_bv  = (const float*)d_in[19];
    const float* a2_fc  = (const float*)d_in[20];
    const float* a2_fcb = (const float*)d_in[21];
    const float* a2_ln_g = (const float*)d_in[22];
    const float* a2_ln_b = (const float*)d_in[23];

    float* ws = (float*)d_ws;
    float* logitsT = ws;                                   // 81920 f
    float* w1  = logitsT + 81920;                          // 81920 f
    float* cf1 = w1 + 81920;                               // 5120 f
    float* cfs = cf1 + 5120;                               // 5120 f
    float* khG = cfs + 5120;                               // 480 f
    float* vhG = khG + 480;                                // 320 f
    float* sPb = vhG + 320;                                // 4 x 65536 f
    ushort_t* aoPb = (ushort_t*)(sPb + 4 * 65536);         // 4 x 4,194,304 ushorts
    ushort_t* Qb = aoPb + 4 * 4194304;
    ushort_t* Kb = Qb + 4194304;
    ushort_t* Vt = Kb + 4194304;
    ushort_t* F  = Vt + 4194304;                           // 16384 ushorts

    k1_logits<<<265, 256, 0, stream>>>(x, wb_w, wb_b, a2_fc, memory,
                                       a1_wk, a1_bk, a1_wv, a1_bv,
                                       logitsT, w1, F, khG, vhG);
    k2b_pool<<<256, 256, 0, stream>>>(x, logitsT, cf1);
    k3_mha1<<<16, 256, 0, stream>>>(cf1, a1_wq, a1_bq, khG, vhG, a1_fc, a1_fcb,
                                    a1_ln_g, a1_ln_b, cfs);
    k5_mfma<<<dim3(256, 3), 256, 0, stream>>>(w1, cfs, a2_wq, a2_bq, a2_wk, a2_bk,
                                              a2_wv, a2_bv, Qb, Kb, Vt);
    k6_attn<<<1024, 256, 0, stream>>>(Qb, Kb, Vt, aoPb, sPb);
    k7_final<<<1024, 256, 0, stream>>>(aoPb, sPb, w1, cfs, F, a2_fcb,
                                       a2_ln_g, a2_ln_b, (float*)d_out);
}

// Round 18
// 185.547 us; speedup vs baseline: 1.0217x; 1.0217x over previous
//
#include <hip/hip_runtime.h>
#include <math.h>

typedef unsigned short ushort_t;
typedef __attribute__((ext_vector_type(8))) short short8;
typedef __attribute__((ext_vector_type(4))) float f32x4;

#define B_  16
#define HW_ 1024
#define C_  64
#define NC_ 5
#define D1_ 96
#define NH_ 4
#define DH_ 64

#define MFMA32(A,B,C) __builtin_amdgcn_mfma_f32_16x16x32_bf16(A,B,C,0,0,0)

__device__ __forceinline__ ushort_t f2bf(float f) {
    unsigned u = __float_as_uint(f);
    u = u + 0x7fffu + ((u >> 16) & 1u);   // round-to-nearest-even
    return (ushort_t)(u >> 16);
}

__device__ __forceinline__ unsigned pack2_trunc(float lo, float hi) {
    return (__float_as_uint(hi) & 0xffff0000u) | (__float_as_uint(lo) >> 16);
}
__device__ __forceinline__ unsigned pack2_rne(float lo, float hi) {
    return ((unsigned)f2bf(hi) << 16) | (unsigned)f2bf(lo);
}
__device__ __forceinline__ float bf_lo(unsigned u) { return __uint_as_float(u << 16); }
__device__ __forceinline__ float bf_hi(unsigned u) { return __uint_as_float(u & 0xffff0000u); }

// async global->LDS, 16B per lane; LDS dest = wave-uniform base + lane*16
__device__ __forceinline__ void gload16(const ushort_t* g, ushort_t* l) {
    __builtin_amdgcn_global_load_lds(
        (const __attribute__((address_space(1))) unsigned int*)g,
        (__attribute__((address_space(3))) unsigned int*)l,
        16, 0, 0);
}

// ---------------- K1: logits + class-softmax (4-wave split) + folded fcT + kh/vh precompute ------
__global__ __launch_bounds__(256) void k1_logits(const float* __restrict__ x,
                                                 const float* __restrict__ wb_w,
                                                 const float* __restrict__ wb_b,
                                                 const float* __restrict__ fc2,
                                                 const float* __restrict__ mem,
                                                 const float* __restrict__ wk, const float* __restrict__ bk,
                                                 const float* __restrict__ wv, const float* __restrict__ bv,
                                                 float* __restrict__ logitsT,
                                                 float* __restrict__ w1,
                                                 ushort_t* __restrict__ F,
                                                 float* __restrict__ khG, float* __restrict__ vhG) {
    int t = threadIdx.x;
    if (blockIdx.x >= 256) {
        int xb2 = blockIdx.x - 256;
        if (xb2 < 8) {               // fcT fragment chunks
            int c = xb2 * 256 + t;
            int l = c & 63, s = (c >> 6) & 7, n = c >> 9;
            int col = n * 16 + (l & 15);
            int k0 = s * 32 + (l >> 4) * 8;
            union { ushort_t us[8]; uint4 u; } pk;
#pragma unroll
            for (int j = 0; j < 8; j++) pk.us[j] = f2bf(fc2[(k0 + j) * 64 + col]);
            *(uint4*)(F + (size_t)c * 8) = pk.u;
        } else {                     // kh/vh precompute (batch-independent)
            for (int idx = t; idx < NC_ * D1_; idx += 256) {
                int i = idx / D1_, k = idx % D1_;
                float a = bk[k];
                for (int d = 0; d < D1_; d++) a += mem[i * D1_ + d] * wk[d * D1_ + k];
                khG[idx] = a;
            }
            for (int idx = t; idx < NC_ * DH_; idx += 256) {
                int i = idx / DH_, dv = idx % DH_;
                float a = bv[dv];
                for (int d = 0; d < D1_; d++) a += mem[i * D1_ + d] * wv[d * DH_ + dv];
                vhG[idx] = a;
            }
        }
        return;
    }
    __shared__ float part[4][64][6];     // pad 6 -> 2-way worst (free)
    int w = t >> 6, lane = t & 63;
    int b = blockIdx.x >> 4;
    int hw = (blockIdx.x & 15) * 64 + lane;
    const float* xb = x + ((size_t)b * C_ + w * 16) * HW_;
    float acc[NC_] = {0.f, 0.f, 0.f, 0.f, 0.f};
#pragma unroll
    for (int c = 0; c < 16; c++) {
        float xv = xb[c * HW_ + hw];
        const float* wp = wb_w + (w * 16 + c) * NC_;   // wave-uniform -> scalar loads
#pragma unroll
        for (int j = 0; j < NC_; j++) acc[j] += xv * wp[j];
    }
#pragma unroll
    for (int j = 0; j < NC_; j++) part[w][lane][j] = acc[j];
    __syncthreads();
    if (w == 0) {
        float a[NC_];
#pragma unroll
        for (int j = 0; j < NC_; j++)
            a[j] = wb_b[j] + acc[j] + part[1][lane][j] + part[2][lane][j] + part[3][lane][j];
        float m = a[0];
#pragma unroll
        for (int j = 1; j < NC_; j++) m = fmaxf(m, a[j]);
        float e[NC_], s = 0.f;
#pragma unroll
        for (int j = 0; j < NC_; j++) { e[j] = __expf(a[j] - m); s += e[j]; }
        float inv = 1.f / s;
        int idx = b * HW_ + hw;
#pragma unroll
        for (int j = 0; j < NC_; j++) {
            logitsT[((size_t)b * NC_ + j) * HW_ + hw] = a[j];
            w1[(size_t)idx * NC_ + j] = e[j] * inv;
        }
    }
}

// ---------------- K2: fused softmax-over-HW + pooling: cf1[b,c,ch] ----------------
__global__ __launch_bounds__(256) void k2b_pool(const float* __restrict__ x,
                                                const float* __restrict__ logitsT,
                                                float* __restrict__ cf1) {
    __shared__ float pl[NC_ * HW_];     // 20 KB
    __shared__ float sinv[NC_];
    int t = threadIdx.x;
    int b = blockIdx.x >> 4, chg = blockIdx.x & 15;
    const float* lp = logitsT + (size_t)b * NC_ * HW_;
    for (int i = t * 4; i < NC_ * HW_; i += 1024)
        *(float4*)(pl + i) = *(const float4*)(lp + i);
    __syncthreads();
    int w = t >> 6, lane = t & 63;
    for (int r = w; r < NC_; r += 4) {
        float m = -1e30f;
        for (int i = lane; i < HW_; i += 64) m = fmaxf(m, pl[r * HW_ + i]);
#pragma unroll
        for (int off = 1; off < 64; off <<= 1) m = fmaxf(m, __shfl_xor(m, off, 64));
        float s = 0.f;
        for (int i = lane; i < HW_; i += 64) {
            float e = __expf(pl[r * HW_ + i] - m);
            pl[r * HW_ + i] = e;
            s += e;
        }
#pragma unroll
        for (int off = 1; off < 64; off <<= 1) s += __shfl_xor(s, off, 64);
        if (lane == 0) sinv[r] = 1.f / s;
    }
    __syncthreads();
    int ch = chg * 4 + w;
    const float* xc = x + ((size_t)b * C_ + ch) * HW_;
    float acc[NC_] = {0.f, 0.f, 0.f, 0.f, 0.f};
#pragma unroll
    for (int i = 0; i < HW_ / 64; i++) {
        int hw = i * 64 + lane;
        float xv = xc[hw];
#pragma unroll
        for (int c = 0; c < NC_; c++) acc[c] += xv * pl[c * HW_ + hw];
    }
#pragma unroll
    for (int c = 0; c < NC_; c++) {
        float a = acc[c];
#pragma unroll
        for (int off = 1; off < 64; off <<= 1) a += __shfl_xor(a, off, 64);
        if (lane == 0) cf1[((size_t)b * NC_ + c) * C_ + ch] = a * sinv[c];
    }
}

// ---------------- K3: MHA1 + residual + LN, per batch (kh/vh loaded from precompute) ----------
__global__ __launch_bounds__(256) void k3_mha1(const float* __restrict__ cf1,
                                               const float* __restrict__ wq, const float* __restrict__ bq,
                                               const float* __restrict__ khG, const float* __restrict__ vhG,
                                               const float* __restrict__ fc, const float* __restrict__ fcb,
                                               const float* __restrict__ lng, const float* __restrict__ lnb,
                                               float* __restrict__ cfs) {
    __shared__ float cs[NC_ * C_];
    __shared__ float kh[NC_ * D1_];
    __shared__ float vh[NC_ * DH_];
    __shared__ float q[NC_ * D1_];
    __shared__ float sc[NC_ * NC_];
    __shared__ float pp[NC_ * NC_];
    __shared__ float o[NC_ * C_];
    __shared__ float z[NC_ * C_];
    __shared__ float mu[NC_], rs[NC_];
    int t = threadIdx.x, b = blockIdx.x;
    for (int i = t; i < NC_ * C_; i += 256) cs[i] = cf1[(size_t)b * NC_ * C_ + i];
    for (int idx = t; idx < NC_ * D1_; idx += 256) kh[idx] = khG[idx];
    for (int idx = t; idx < NC_ * DH_; idx += 256) vh[idx] = vhG[idx];
    __syncthreads();
    for (int idx = t; idx < NC_ * D1_; idx += 256) {
        int i = idx / D1_, k = idx % D1_;
        float a = bq[k];
        for (int c = 0; c < C_; c++) a += cs[i * C_ + c] * wq[c * D1_ + k];
        q[idx] = a;
    }
    __syncthreads();
    if (t < NC_ * NC_) {
        int i = t / NC_, j = t % NC_;
        float a = 0.f;
        for (int k = 0; k < D1_; k++) a += q[i * D1_ + k] * kh[j * D1_ + k];
        sc[t] = a * 0.1020620726159657f;     // 1/sqrt(96)
    }
    __syncthreads();
    if (t < NC_) {
        float m = sc[t * NC_];
        for (int j = 1; j < NC_; j++) m = fmaxf(m, sc[t * NC_ + j]);
        float e[NC_], s = 0.f;
        for (int j = 0; j < NC_; j++) { e[j] = __expf(sc[t * NC_ + j] - m); s += e[j]; }
        float inv = 1.f / s;
        for (int j = 0; j < NC_; j++) pp[t * NC_ + j] = e[j] * inv;
    }
    __syncthreads();
    for (int idx = t; idx < NC_ * C_; idx += 256) {
        int i = idx / C_, dv = idx % C_;
        float a = 0.f;
        for (int j = 0; j < NC_; j++) a += pp[i * NC_ + j] * vh[j * C_ + dv];
        o[idx] = a;
    }
    __syncthreads();
    for (int idx = t; idx < NC_ * C_; idx += 256) {
        int i = idx / C_, dd = idx % C_;
        float a = fcb[dd] + cs[idx];
        for (int c2 = 0; c2 < C_; c2++) a += o[i * C_ + c2] * fc[c2 * C_ + dd];
        z[idx] = a;
    }
    __syncthreads();
    if (t < NC_) {
        float s = 0.f;
        for (int d = 0; d < C_; d++) s += z[t * C_ + d];
        float mm = s / C_;
        float v = 0.f;
        for (int d = 0; d < C_; d++) { float dd2 = z[t * C_ + d] - mm; v += dd2 * dd2; }
        mu[t] = mm; rs[t] = rsqrtf(v / C_ + 1e-6f);
    }
    __syncthreads();
    for (int idx = t; idx < NC_ * C_; idx += 256) {
        int i = idx / C_, dd = idx % C_;
        cfs[(size_t)b * NC_ * C_ + idx] = (z[idx] - mu[i]) * rs[i] * lng[dd] + lnb[dd];
    }
}

// ---------------- K5: MFMA projection GEMM (inline redistribution + Q/K/V) — R13 version ----------
__global__ __launch_bounds__(256) void k5_mfma(const float* __restrict__ w1,
                                               const float* __restrict__ cfs,
                                               const float* __restrict__ wq, const float* __restrict__ bq,
                                               const float* __restrict__ wk, const float* __restrict__ bk,
                                               const float* __restrict__ wv, const float* __restrict__ bv,
                                               ushort_t* __restrict__ Qb, ushort_t* __restrict__ Kb,
                                               ushort_t* __restrict__ Vt) {
    __shared__ ushort_t Af[64][68];      // cf rows, bf16
    __shared__ ushort_t Wt[256][68];     // W^T [n][k], bf16
    int t = threadIdx.x;
    int which = blockIdx.y;
    int m0 = blockIdx.x * 64;
    int b = m0 >> 10, lbase = m0 & 1023;
    {
        int r = t >> 2, ks = (t & 3) * 16;
        const float* cp = cfs + (size_t)b * NC_ * C_;
        const float* w1p = w1 + (size_t)(m0 + r) * NC_;
        float v0 = w1p[0], v1 = w1p[1], v2 = w1p[2], v3 = w1p[3], v4 = w1p[4];
#pragma unroll
        for (int j = 0; j < 16; j += 2) {
            int k = ks + j;
            float e0 = v0 * cp[k]       + v1 * cp[64 + k]     + v2 * cp[128 + k]
                     + v3 * cp[192 + k] + v4 * cp[256 + k];
            float e1 = v0 * cp[k + 1]     + v1 * cp[64 + k + 1] + v2 * cp[128 + k + 1]
                     + v3 * cp[192 + k + 1] + v4 * cp[256 + k + 1];
            *(unsigned*)&Af[r][k] = pack2_rne(e0, e1);
        }
    }
    const float* W = (which == 0) ? wq : (which == 1) ? wk : wv;
    {
        int n = t;
#pragma unroll
        for (int k = 0; k < 64; k += 2) {
            *(unsigned*)&Wt[n][k] = pack2_rne(W[k * 256 + n], W[(k + 1) * 256 + n]);
        }
    }
    __syncthreads();
    int lane = t & 63, w = t >> 6;
    int l15 = lane & 15, quad = lane >> 4;
    if (which < 2) {
        const float* bias = (which == 0) ? bq : bk;
        float scale = (which == 0) ? 0.18033688011112042f : 1.0f;  // log2e/8 folded into Q
        ushort_t* dst = (which == 0) ? Qb : Kb;
        short8 a0[4], a1[4];
#pragma unroll
        for (int mi = 0; mi < 4; mi++) {
            a0[mi] = *(const short8*)&Af[mi * 16 + l15][quad * 8];
            a1[mi] = *(const short8*)&Af[mi * 16 + l15][32 + quad * 8];
        }
#pragma unroll
        for (int nt = 0; nt < 4; nt++) {
            int ni = w * 4 + nt;
            short8 b0 = *(const short8*)&Wt[ni * 16 + l15][quad * 8];
            short8 b1 = *(const short8*)&Wt[ni * 16 + l15][32 + quad * 8];
            int n = ni * 16 + l15;
            float bb = bias[n];
            int h = n >> 6, dd = n & 63;
#pragma unroll
            for (int mi = 0; mi < 4; mi++) {
                f32x4 z = {0, 0, 0, 0};
                f32x4 dv4 = MFMA32(a0[mi], b0, z);
                dv4 = MFMA32(a1[mi], b1, dv4);
                size_t base = ((size_t)(b * NH_ + h) * HW_ + (lbase + mi * 16 + quad * 4)) * DH_ + dd;
#pragma unroll
                for (int r = 0; r < 4; r++)
                    dst[base + (size_t)r * DH_] = f2bf((dv4[r] + bb) * scale);
            }
        }
    } else {
        short8 a0[4], a1[4];
#pragma unroll
        for (int mt = 0; mt < 4; mt++) {
            int mi = w * 4 + mt;
            a0[mt] = *(const short8*)&Wt[mi * 16 + l15][quad * 8];
            a1[mt] = *(const short8*)&Wt[mi * 16 + l15][32 + quad * 8];
        }
#pragma unroll
        for (int nt = 0; nt < 4; nt++) {
            short8 b0 = *(const short8*)&Af[nt * 16 + l15][quad * 8];
            short8 b1 = *(const short8*)&Af[nt * 16 + l15][32 + quad * 8];
#pragma unroll
            for (int mt = 0; mt < 4; mt++) {
                int mi = w * 4 + mt;
                f32x4 z = {0, 0, 0, 0};
                f32x4 dv4 = MFMA32(a0[mt], b0, z);
                dv4 = MFMA32(a1[mt], b1, dv4);
                int h = mi >> 2;
#pragma unroll
                for (int r = 0; r < 4; r++) {
                    int nw = mi * 16 + quad * 4 + r;
                    int dv = nw & 63;
                    Vt[((size_t)(b * NH_ + h) * DH_ + dv) * HW_ + lbase + nt * 16 + l15] =
                        f2bf(dv4[r] + bv[nw]);
                }
            }
        }
    }
}

// ---------------- K6: flash attention — async LDS staging, split-K2, 4 q-tiles/wave (R16) ----------
__global__ __launch_bounds__(256) void k6_attn(const ushort_t* __restrict__ Qb,
                                               const ushort_t* __restrict__ Kb,
                                               const ushort_t* __restrict__ Vt,
                                               ushort_t* __restrict__ aoPb,
                                               float* __restrict__ sPb) {
    __shared__ ushort_t Kst[2][8][512];     // 16 KB
    int t = threadIdx.x;
    int w = t >> 6;
    int lane = t & 63;
    int l15 = lane & 15;
    int quad = lane >> 4;
    int L = blockIdx.x;
    int bh = ((L >> 3) & 7) * 8 + (L & 7);
    int khalf = (L >> 6) & 1;
    int qt = L >> 7;                     // 0..3
    int b = bh >> 2, h = bh & 3;
    const ushort_t* Qp = Qb + (size_t)bh * HW_ * DH_;
    const ushort_t* Kp = Kb + (size_t)bh * HW_ * DH_;
    const ushort_t* Vp = Vt + (size_t)bh * DH_ * HW_;
    int row0 = qt * 256 + w * 16;
    short8 q0[4], q1[4];
#pragma unroll
    for (int tl = 0; tl < 4; tl++) {
        const ushort_t* qp = Qp + (size_t)(row0 + tl * 64 + l15) * DH_ + quad * 8;
        q0[tl] = *(const short8*)(qp);
        q1[tl] = *(const short8*)(qp + 32);
    }
    int f0 = ((l15 >> 2) * 8) + (l15 & 3);
    int kstart = khalf * 512;
    const ushort_t* K0p = Kp + (size_t)(kstart + f0) * DH_ + quad * 8;
    const ushort_t* K1p = Kp + (size_t)(kstart + f0 + 4) * DH_ + quad * 8;
    const ushort_t* Vp0 = Vp + (size_t)(0 * 16 + l15) * HW_ + kstart + quad * 8;
    const ushort_t* Vp1 = Vp + (size_t)(1 * 16 + l15) * HW_ + kstart + quad * 8;
    const ushort_t* Vp2 = Vp + (size_t)(2 * 16 + l15) * HW_ + kstart + quad * 8;
    const ushort_t* Vp3 = Vp + (size_t)(3 * 16 + l15) * HW_ + kstart + quad * 8;
    auto stage = [&](int kt, int bb) {
        size_t koff = (size_t)kt * 32 * DH_;
        int kb32 = kt * 32;
        if (w == 0) {
            gload16(K0p + koff,      &Kst[bb][0][0]);
            gload16(K0p + koff + 32, &Kst[bb][1][0]);
        } else if (w == 1) {
            gload16(K1p + koff,      &Kst[bb][2][0]);
            gload16(K1p + koff + 32, &Kst[bb][3][0]);
        } else if (w == 2) {
            gload16(Vp0 + kb32, &Kst[bb][4][0]);
            gload16(Vp1 + kb32, &Kst[bb][5][0]);
        } else {
            gload16(Vp2 + kb32, &Kst[bb][6][0]);
            gload16(Vp3 + kb32, &Kst[bb][7][0]);
        }
    };
    const short ONE = (short)0x3F80;      // bf16 1.0
    short8 ones = {ONE, ONE, ONE, ONE, ONE, ONE, ONE, ONE};
    f32x4 o0[4], o1[4], o2[4], o3[4], oS[4];
#pragma unroll
    for (int tl = 0; tl < 4; tl++) {
        o0[tl] = (f32x4){0,0,0,0}; o1[tl] = (f32x4){0,0,0,0};
        o2[tl] = (f32x4){0,0,0,0}; o3[tl] = (f32x4){0,0,0,0};
        oS[tl] = (f32x4){0,0,0,0};
    }
    stage(0, 0);
    for (int kt = 0; kt < 16; kt++) {
        int bb = kt & 1;
        __syncthreads();                     // stage(kt) complete
        if (kt < 15) stage(kt + 1, bb ^ 1);  // flies during compute below
        const ushort_t* S = &Kst[bb][0][0];
        short8 ka0 = *(const short8*)(S + 0 * 512 + lane * 8);
        short8 ka1 = *(const short8*)(S + 1 * 512 + lane * 8);
        short8 kb0 = *(const short8*)(S + 2 * 512 + lane * 8);
        short8 kb1 = *(const short8*)(S + 3 * 512 + lane * 8);
        short8 v0  = *(const short8*)(S + 4 * 512 + lane * 8);
        short8 v1  = *(const short8*)(S + 5 * 512 + lane * 8);
        short8 v2  = *(const short8*)(S + 6 * 512 + lane * 8);
        short8 v3  = *(const short8*)(S + 7 * 512 + lane * 8);
        f32x4 z = {0,0,0,0};
#pragma unroll
        for (int tl = 0; tl < 4; tl++) {
            f32x4 s0 = MFMA32(ka0, q0[tl], z);  s0 = MFMA32(ka1, q1[tl], s0);
            f32x4 s1 = MFMA32(kb0, q0[tl], z);  s1 = MFMA32(kb1, q1[tl], s1);
            float p0 = exp2f(s0[0]), p1 = exp2f(s0[1]), p2 = exp2f(s0[2]), p3 = exp2f(s0[3]);
            float p4 = exp2f(s1[0]), p5 = exp2f(s1[1]), p6 = exp2f(s1[2]), p7 = exp2f(s1[3]);
            union { short8 v; unsigned u[4]; } pf;
            pf.u[0] = pack2_trunc(p0, p1);  pf.u[1] = pack2_trunc(p2, p3);
            pf.u[2] = pack2_trunc(p4, p5);  pf.u[3] = pack2_trunc(p6, p7);
            o0[tl] = MFMA32(v0, pf.v, o0[tl]);
            o1[tl] = MFMA32(v1, pf.v, o1[tl]);
            o2[tl] = MFMA32(v2, pf.v, o2[tl]);
            o3[tl] = MFMA32(v3, pf.v, o3[tl]);
            oS[tl] = MFMA32(ones, pf.v, oS[tl]);
        }
    }
    ushort_t* aoP = aoPb + (size_t)khalf * 4194304;
    float* sP = sPb + (size_t)khalf * 65536;
#pragma unroll
    for (int tl = 0; tl < 4; tl++) {
        int rowg = row0 + tl * 64 + l15;
        ushort_t* aop = aoP + ((size_t)(b * HW_ + rowg)) * 256 + h * 64 + quad * 4;
        uint2 u;
        u.x = pack2_trunc(o0[tl][0], o0[tl][1]); u.y = pack2_trunc(o0[tl][2], o0[tl][3]);
        *(uint2*)(aop + 0) = u;
        u.x = pack2_trunc(o1[tl][0], o1[tl][1]); u.y = pack2_trunc(o1[tl][2], o1[tl][3]);
        *(uint2*)(aop + 16) = u;
        u.x = pack2_trunc(o2[tl][0], o2[tl][1]); u.y = pack2_trunc(o2[tl][2], o2[tl][3]);
        *(uint2*)(aop + 32) = u;
        u.x = pack2_trunc(o3[tl][0], o3[tl][1]); u.y = pack2_trunc(o3[tl][2], o3[tl][3]);
        *(uint2*)(aop + 48) = u;
        if (quad == 0)
            sP[(size_t)(b * HW_ + rowg) * NH_ + h] = oS[tl][0];
    }
}

// ---------------- K7: combine 2 partials -> MFMA GEMM vs fc + residual + LN -> out ----------------
__global__ __launch_bounds__(256) void k7_final(const ushort_t* __restrict__ aoPb,
                                                const float* __restrict__ sPb,
                                                const float* __restrict__ w1,
                                                const float* __restrict__ cfs,
                                                const ushort_t* __restrict__ F,
                                                const float* __restrict__ fcb,
                                                const float* __restrict__ lng, const float* __restrict__ lnb,
                                                float* __restrict__ out) {
    __shared__ ushort_t Afr[512 * 8];     // 8 KB fragment-order A
    __shared__ float rinv[64];
    __shared__ float T[16][68];           // MFMA result f32 (padded)
    __shared__ float To[64 * 17];         // output transpose buffer
    int t = threadIdx.x, w = t >> 6, lane = t & 63;
    int m0 = blockIdx.x * 16, b = m0 >> 10;   // m0 is the GLOBAL row index
    if (t < 64) {
        int row = t >> 2, hh = t & 3;
        size_t si = (size_t)(m0 + row) * NH_ + hh;
        float s = sPb[si] + sPb[65536 + si];
        rinv[t] = 1.f / s;
    }
    __syncthreads();
#pragma unroll
    for (int cc = t; cc < 512; cc += 256) {
        int s = cc >> 6, l = cc & 63;
        int row = l & 15, col0 = s * 32 + (l >> 4) * 8;
        int hh = col0 >> 6;
        size_t base = (size_t)(m0 + row) * 256 + col0;
        uint4 a = *(const uint4*)(aoPb + base);
        uint4 c4 = *(const uint4*)(aoPb + 4194304 + base);
        float r = rinv[row * 4 + hh];
        uint4 pk;
        pk.x = pack2_trunc((bf_lo(a.x) + bf_lo(c4.x)) * r, (bf_hi(a.x) + bf_hi(c4.x)) * r);
        pk.y = pack2_trunc((bf_lo(a.y) + bf_lo(c4.y)) * r, (bf_hi(a.y) + bf_hi(c4.y)) * r);
        pk.z = pack2_trunc((bf_lo(a.z) + bf_lo(c4.z)) * r, (bf_hi(a.z) + bf_hi(c4.z)) * r);
        pk.w = pack2_trunc((bf_lo(a.w) + bf_lo(c4.w)) * r, (bf_hi(a.w) + bf_hi(c4.w)) * r);
        *(uint4*)&Afr[(size_t)cc * 8] = pk;
    }
    __syncthreads();
    f32x4 acc = {0, 0, 0, 0};
#pragma unroll
    for (int s = 0; s < 8; s++) {
        short8 a = *(const short8*)&Afr[(s * 64 + lane) * 8];
        short8 bf8 = *(const short8*)(F + ((size_t)(w * 8 + s) * 64 + lane) * 8);
        acc = MFMA32(a, bf8, acc);
    }
    {
        int l15 = lane & 15, quad = lane >> 4;
#pragma unroll
        for (int r = 0; r < 4; r++) T[quad * 4 + r][w * 16 + l15] = acc[r];
    }
    __syncthreads();
    int d = lane;
    float g = lng[d], be = lnb[d], bias = fcb[d];
    const float* cp = cfs + (size_t)b * NC_ * C_;
#pragma unroll
    for (int j = 0; j < 4; j++) {
        int row = w * 4 + j;
        const float* w1p = w1 + (size_t)(m0 + row) * NC_;
        float a = bias + T[row][d];
#pragma unroll
        for (int c = 0; c < NC_; c++) a += w1p[c] * cp[c * 64 + d];
        float s1 = a, s2 = a * a;
#pragma unroll
        for (int off = 1; off < 64; off <<= 1) {
            s1 += __shfl_xor(s1, off, 64);
            s2 += __shfl_xor(s2, off, 64);
        }
        float mu = s1 * (1.f / 64.f);
        float var = s2 * (1.f / 64.f) - mu * mu;
        float rstd = rsqrtf(var + 1e-6f);
        To[d * 17 + row] = (a - mu) * rstd * g + be;
    }
    __syncthreads();
    int ch = t >> 2, part = t & 3;
    int hw0 = m0 & 1023;
    float4 v = {To[ch * 17 + part * 4 + 0], To[ch * 17 + part * 4 + 1],
                To[ch * 17 + part * 4 + 2], To[ch * 17 + part * 4 + 3]};
    *(float4*)&out[((size_t)b * 64 + ch) * 1024 + hw0 + part * 4] = v;
}

// ---------------- launcher: 6 dispatches ----------------
extern "C" void kernel_launch(void* const* d_in, const int* in_sizes, int n_in,
                              void* d_out, int out_size, void* d_ws, size_t ws_size,
                              hipStream_t stream) {
    const float* x      = (const float*)d_in[0];
    const float* memory = (const float*)d_in[1];
    const float* wb_w   = (const float*)d_in[2];
    const float* wb_b   = (const float*)d_in[3];
    const float* a1_wq  = (const float*)d_in[4];
    const float* a1_bq  = (const float*)d_in[5];
    const float* a1_wk  = (const float*)d_in[6];
    const float* a1_bk  = (const float*)d_in[7];
    const float* a1_wv  = (const float*)d_in[8];
    const float* a1_bv  = (const float*)d_in[9];
    const float* a1_fc  = (const float*)d_in[10];
    const float* a1_fcb = (const float*)d_in[11];
    const float* a1_ln_g = (const float*)d_in[12];
    const float* a1_ln_b = (const float*)d_in[13];
    const float* a2_wq  = (const float*)d_in[14];
    const float* a2_bq  = (const float*)d_in[15];
    const float* a2_wk  = (const float*)d_in[16];
    const float* a2_bk  = (const float*)d_in[17];
    const float* a2_wv  = (const float*)d_in[18];
    const float* a2_bv  = (const float*)d_in[19];
    const float* a2_fc  = (const float*)d_in[20];
    const float* a2_fcb = (const float*)d_in[21];
    const float* a2_ln_g = (const float*)d_in[22];
    const float* a2_ln_b = (const float*)d_in[23];

    float* ws = (float*)d_ws;
    float* logitsT = ws;                                   // 81920 f
    float* w1  = logitsT + 81920;                          // 81920 f
    float* cf1 = w1 + 81920;                               // 5120 f
    float* cfs = cf1 + 5120;                               // 5120 f
    float* khG = cfs + 5120;                               // 480 f
    float* vhG = khG + 480;                                // 320 f
    float* sPb = vhG + 320;                                // 2 x 65536 f
    ushort_t* aoPb = (ushort_t*)(sPb + 2 * 65536);         // 2 x 4,194,304 ushorts
    ushort_t* Qb = aoPb + 2 * 4194304;
    ushort_t* Kb = Qb + 4194304;
    ushort_t* Vt = Kb + 4194304;
    ushort_t* F  = Vt + 4194304;                           // 16384 ushorts

    k1_logits<<<265, 256, 0, stream>>>(x, wb_w, wb_b, a2_fc, memory,
                                       a1_wk, a1_bk, a1_wv, a1_bv,
                                       logitsT, w1, F, khG, vhG);
    k2b_pool<<<256, 256, 0, stream>>>(x, logitsT, cf1);
    k3_mha1<<<16, 256, 0, stream>>>(cf1, a1_wq, a1_bq, khG, vhG, a1_fc, a1_fcb,
                                    a1_ln_g, a1_ln_b, cfs);
    k5_mfma<<<dim3(256, 3), 256, 0, stream>>>(w1, cfs, a2_wq, a2_bq, a2_wk, a2_bk,
                                              a2_wv, a2_bv, Qb, Kb, Vt);
    k6_attn<<<512, 256, 0, stream>>>(Qb, Kb, Vt, aoPb, sPb);
    k7_final<<<1024, 256, 0, stream>>>(aoPb, sPb, w1, cfs, F, a2_fcb,
                                       a2_ln_g, a2_ln_b, (float*)d_out);
}